// Round 10
// baseline (107.538 us; speedup 1.0000x reference)
//
#include <hip/hip_runtime.h>

// Problem dims
constexpr int SEQ   = 2048;
constexpr int BATCH = 2;
constexpr int EMB   = 1024;
constexpr int NH    = 16;
constexpr int HDIM  = 64;
constexpr int MROWS = SEQ * BATCH;   // 4096
constexpr int KDIM  = EMB;           // 1024
constexpr int NCOLS = 3 * EMB;       // 3072

typedef __bf16 bf16x8 __attribute__((ext_vector_type(8)));
typedef __bf16 bf16x4 __attribute__((ext_vector_type(4)));
typedef float  f32x4  __attribute__((ext_vector_type(4)));
typedef float  f32x16 __attribute__((ext_vector_type(16)));
typedef unsigned int u32;
typedef unsigned int u32x4 __attribute__((ext_vector_type(4)));

__device__ __forceinline__ u32 cvt_pk_bf16(float lo, float hi) {
  u32 r;
  asm("v_cvt_pk_bf16_f32 %0, %1, %2" : "=v"(r) : "v"(lo), "v"(hi));
  return r;
}
__device__ __forceinline__ void pl32_swap(u32& a, u32& b) {
  asm("v_permlane32_swap_b32 %0, %1" : "+v"(a), "+v"(b));
}
// async global->LDS, 16B per lane; LDS dest = wave-uniform base + lane*16
__device__ __forceinline__ void g2l16(const __bf16* g, __bf16* l) {
  __builtin_amdgcn_global_load_lds(
      (const __attribute__((address_space(1))) void*)g,
      (__attribute__((address_space(3))) void*)l, 16, 0, 0);
}

// ---------------------------------------------------------------------------
// fp32 -> bf16 cast for BOTH x and Wqkv in one launch
// ---------------------------------------------------------------------------
constexpr int N4X = (MROWS * KDIM) / 4;   // 1048576
constexpr int N4W = (NCOLS * KDIM) / 4;   // 786432
__global__ __launch_bounds__(256) void cvt_all(
    const float* __restrict__ x, const float* __restrict__ Wq,
    __bf16* __restrict__ Xb, __bf16* __restrict__ Wb) {
  int stride = gridDim.x * blockDim.x;
  for (int i = blockIdx.x * blockDim.x + threadIdx.x; i < N4X + N4W; i += stride) {
    const float4 v = (i < N4X) ? reinterpret_cast<const float4*>(x)[i]
                               : reinterpret_cast<const float4*>(Wq)[i - N4X];
    bf16x4 o;
    o[0] = (__bf16)v.x; o[1] = (__bf16)v.y; o[2] = (__bf16)v.z; o[3] = (__bf16)v.w;
    if (i < N4X) reinterpret_cast<bf16x4*>(Xb)[i] = o;
    else         reinterpret_cast<bf16x4*>(Wb)[i - N4X] = o;
  }
}

// ---------------------------------------------------------------------------
// QKV projection (R4-verified): 128x128 tile, BK=32, 2-phase double-buffered
// global_load_lds staging.
// ---------------------------------------------------------------------------
__global__ __launch_bounds__(256, 4) void qkv_gemm(
    const __bf16* __restrict__ Xb, const __bf16* __restrict__ Wb,
    const float* __restrict__ bqkv,
    __bf16* __restrict__ Qb, __bf16* __restrict__ Kb, __bf16* __restrict__ Vt) {
  __shared__ __attribute__((aligned(16))) __bf16 Al[2][128 * 32];
  __shared__ __attribute__((aligned(16))) __bf16 Bl[2][128 * 32];

  const int tid  = threadIdx.x;
  const int lane = tid & 63;
  const int w    = tid >> 6;
  const int wm   = w >> 1, wn = w & 1;

  const int bid  = blockIdx.x;
  const int wgid = (bid & 7) * 96 + (bid >> 3);
  const int nx   = wgid % 24;
  const int nyy  = wgid / 24;
  const int m0   = nyy * 128;
  const int n0   = nx * 128;

  f32x4 acc[4][4] = {};

  auto stage = [&](int buf, int kt) {
#pragma unroll
    for (int c = 0; c < 2; ++c) {
      const int u   = (w * 2 + c) * 64 + lane;
      const int row = u >> 2;
      const int sc  = ((u & 3) ^ ((row >> 1) & 3)) * 8;
      g2l16(&Xb[(size_t)(m0 + row) * KDIM + kt * 32 + sc], &Al[buf][(w * 2 + c) * 512]);
      g2l16(&Wb[(size_t)(n0 + row) * KDIM + kt * 32 + sc], &Bl[buf][(w * 2 + c) * 512]);
    }
  };

  stage(0, 0);
  __syncthreads();

  const int l15 = lane & 15, hi4 = lane >> 4;
  const int cswz = (hi4 ^ ((l15 >> 1) & 3)) * 8;

  for (int kt = 0; kt < KDIM / 32; ++kt) {
    const int buf = kt & 1;
    if (kt + 1 < KDIM / 32) stage(buf ^ 1, kt + 1);

    bf16x8 af[4], bfr[4];
#pragma unroll
    for (int i = 0; i < 4; ++i) {
      af[i]  = *reinterpret_cast<const bf16x8*>(&Al[buf][(wm * 64 + i * 16 + l15) * 32 + cswz]);
      bfr[i] = *reinterpret_cast<const bf16x8*>(&Bl[buf][(wn * 64 + i * 16 + l15) * 32 + cswz]);
    }
    __builtin_amdgcn_s_setprio(1);
#pragma unroll
    for (int i = 0; i < 4; ++i)
#pragma unroll
      for (int j = 0; j < 4; ++j)
        acc[i][j] = __builtin_amdgcn_mfma_f32_16x16x32_bf16(af[i], bfr[j], acc[i][j], 0, 0, 0);
    __builtin_amdgcn_s_setprio(0);
    __syncthreads();
  }

  const float QSCALE = 0.18033688011112042f;  // 0.125 * log2(e)
#pragma unroll
  for (int j = 0; j < 4; ++j) {
    const int f    = n0 + wn * 64 + j * 16 + l15;
    const float bias = bqkv[f];
    const int sec  = f >> 10;
    const int hd   = f & 1023;
    const int h    = hd >> 6, d = hd & 63;
#pragma unroll
    for (int i = 0; i < 4; ++i) {
#pragma unroll
      for (int r = 0; r < 4; ++r) {
        const int mm = m0 + wm * 64 + i * 16 + hi4 * 4 + r;
        const int s_ = mm >> 1, b_ = mm & 1;
        const int bh = b_ * NH + h;
        const float val = acc[i][j][r] + bias;
        if (sec == 0) {
          Qb[((size_t)bh * SEQ + s_) * HDIM + d] = (__bf16)(val * QSCALE);
        } else if (sec == 1) {
          Kb[((size_t)bh * SEQ + s_) * HDIM + d] = (__bf16)val;
        } else {
          Vt[((size_t)bh * HDIM + d) * SEQ + s_] = (__bf16)val;
        }
      }
    }
  }
}

// ---------------------------------------------------------------------------
// Flash attention v10: t-split across wave pairs. Block = 64 q (2 q-sets),
// 4 waves = (qs, ts); wave (qs,ts) handles t-rows ts*32..ts*32+31 of every
// 64-t tile -> per-wave work halves (4 K-reads, 8 MFMA, 16 exp2, 8 cvt).
// Max-free softmax (R9-verified) makes the final merge a plain add in LDS.
// Main-loop skeleton (stage/prefetch/setprio fences/barrier) identical to R9.
// 1024 blocks -> 4 blocks/CU, 4 waves/SIMD.
// ---------------------------------------------------------------------------
__global__ __launch_bounds__(256) void attn_fwd(
    const __bf16* __restrict__ Qb, const __bf16* __restrict__ Kb,
    const __bf16* __restrict__ Vt, float* __restrict__ out) {
  __shared__ __attribute__((aligned(16))) __bf16 lds[16384];  // 2 x (K 8KB + V 8KB)

  const int tid  = threadIdx.x;
  const int lane = tid & 63;
  const int w    = tid >> 6;   // 0..3
  const int qs   = w & 1;      // q-set within block
  const int ts   = w >> 1;     // t-half within each staged tile
  const int lq   = lane & 31;
  const int hi   = lane >> 5;

  // bijective XCD swizzle: 1024 blocks, 128 per XCD -> 4 consecutive bh per XCD
  const int bid  = blockIdx.x;
  const int wgid = (bid & 7) * 128 + (bid >> 3);
  const int qi   = wgid & 31;
  const int bh   = wgid >> 5;
  const int b_   = bh >> 4, h = bh & 15;
  const int q0   = qi * 64 + qs * 32;

  const __bf16* Qp = Qb + (size_t)bh * SEQ * HDIM;
  const __bf16* Kp = Kb + (size_t)bh * SEQ * HDIM;
  const __bf16* Vp = Vt + (size_t)bh * HDIM * SEQ;

  // Q persistent: QK^T B-operand, col q=lane&31, k(d)=ks*16+hi*8+j
  bf16x8 qf[4];
#pragma unroll
  for (int ks = 0; ks < 4; ++ks)
    qf[ks] = *reinterpret_cast<const bf16x8*>(&Qp[(size_t)(q0 + lq) * HDIM + ks * 16 + hi * 8]);

  f32x16 acc0 = {}, acc1 = {};
  float l = 0.f;

  auto stage = [&](int b, int t0) {
#pragma unroll
    for (int c = 0; c < 2; ++c) {
      const int u   = (w * 2 + c) * 64 + lane;            // 0..511 chunks
      const int row = u >> 3;
      const int sc  = ((u & 7) * 8) ^ ((row & 7) << 3);
      g2l16(Kp + (size_t)(t0 + row) * HDIM + sc, lds + b * 8192 + (w * 2 + c) * 512);
      g2l16(Vp + (size_t)row * SEQ + t0 + sc,    lds + b * 8192 + 4096 + (w * 2 + c) * 512);
    }
  };

  stage(0, 0);
  __syncthreads();
  int cur = 0;

  const int krow = ts * 32 + lq;  // this wave's K t-row within the tile

  for (int t0 = 0; t0 < SEQ; t0 += 64) {
    if (t0 + 64 < SEQ) stage(cur ^ 1, t0 + 64);  // prefetch flies under compute
    const __bf16* kb = lds + cur * 8192;
    const __bf16* vb = kb + 4096;

    // ---- S = K(rows ts*32..+31) · Q^T : one 32x32 tile, 4 k-steps over d ----
    f32x16 S0 = {};
    __builtin_amdgcn_s_setprio(1);
#pragma unroll
    for (int ks = 0; ks < 4; ++ks) {
      const int colb = ks * 16 + hi * 8;
      bf16x8 k0 = *reinterpret_cast<const bf16x8*>(&kb[krow * 64 + (colb ^ ((krow & 7) << 3))]);
      S0 = __builtin_amdgcn_mfma_f32_32x32x16_bf16(k0, qf[ks], S0, 0, 0, 0);
    }
    __builtin_amdgcn_s_setprio(0);

    // ---- max-free softmax: P = exp2(S), row-sum into l ----
    float r0 = 0.f, r1 = 0.f, r2 = 0.f, r3 = 0.f;
#pragma unroll
    for (int i = 0; i < 4; ++i) {
      S0[i]      = __builtin_amdgcn_exp2f(S0[i]);      r0 += S0[i];
      S0[i + 4]  = __builtin_amdgcn_exp2f(S0[i + 4]);  r1 += S0[i + 4];
      S0[i + 8]  = __builtin_amdgcn_exp2f(S0[i + 8]);  r2 += S0[i + 8];
      S0[i + 12] = __builtin_amdgcn_exp2f(S0[i + 12]); r3 += S0[i + 12];
    }
    l += (r0 + r1) + (r2 + r3);

    // ---- P -> bf16 B-fragments for PV (cvt_pk + permlane32_swap) ----
    bf16x8 pw[2];
    {
#pragma unroll
      for (int kk = 0; kk < 2; ++kk) {
        u32 a0 = cvt_pk_bf16(S0[kk * 8 + 0], S0[kk * 8 + 1]);
        u32 b0 = cvt_pk_bf16(S0[kk * 8 + 4], S0[kk * 8 + 5]);
        u32 a1 = cvt_pk_bf16(S0[kk * 8 + 2], S0[kk * 8 + 3]);
        u32 b1 = cvt_pk_bf16(S0[kk * 8 + 6], S0[kk * 8 + 7]);
        pl32_swap(a0, b0);
        pl32_swap(a1, b1);
        u32x4 wv; wv[0] = a0; wv[1] = a1; wv[2] = b0; wv[3] = b1;
        pw[kk] = __builtin_bit_cast(bf16x8, wv);
      }
    }

    // ---- O^T(partial) += V^T · P^T : 2 d-blocks x 2 k-steps over t-half ----
    __builtin_amdgcn_s_setprio(1);
#pragma unroll
    for (int ks = 0; ks < 2; ++ks) {
      const int colb = ts * 32 + ks * 16 + hi * 8;
      bf16x8 v0 = *reinterpret_cast<const bf16x8*>(&vb[lq * 64        + (colb ^ ((lq & 7) << 3))]);
      bf16x8 v1 = *reinterpret_cast<const bf16x8*>(&vb[(32 + lq) * 64 + (colb ^ ((lq & 7) << 3))]);
      acc0 = __builtin_amdgcn_mfma_f32_32x32x16_bf16(v0, pw[ks], acc0, 0, 0, 0);
      acc1 = __builtin_amdgcn_mfma_f32_32x32x16_bf16(v1, pw[ks], acc1, 0, 0, 0);
    }
    __builtin_amdgcn_s_setprio(0);

    __syncthreads();  // readers done with cur + prefetch arrived
    cur ^= 1;
  }

  // ---- merge the two t-halves per q-set via LDS (plain add: max-free) ----
  float* xch = reinterpret_cast<float*>(lds);  // 32KB, quiescent after last barrier
  const int base = qs * 64 * 33 + lane * 33;   // stride 33: conflict-free
  if (ts == 1) {
#pragma unroll
    for (int i = 0; i < 16; ++i) { xch[base + i] = acc0[i]; xch[base + 16 + i] = acc1[i]; }
    xch[base + 32] = l;
  }
  __syncthreads();
  if (ts == 0) {
#pragma unroll
    for (int i = 0; i < 16; ++i) { acc0[i] += xch[base + i]; acc1[i] += xch[base + 16 + i]; }
    l += xch[base + 32];

    // ---- epilogue: combine l across lane halves, normalize, store fp32 ----
    l += __shfl_xor(l, 32);
    const float inv = 1.0f / l;
    const int s_ = q0 + lq;
    float* op = out + ((size_t)s_ * BATCH + b_) * EMB + h * HDIM;
#pragma unroll
    for (int rr = 0; rr < 4; ++rr) {
      float4 o0 = {acc0[4 * rr] * inv, acc0[4 * rr + 1] * inv,
                   acc0[4 * rr + 2] * inv, acc0[4 * rr + 3] * inv};
      *reinterpret_cast<float4*>(&op[8 * rr + 4 * hi]) = o0;
      float4 o1 = {acc1[4 * rr] * inv, acc1[4 * rr + 1] * inv,
                   acc1[4 * rr + 2] * inv, acc1[4 * rr + 3] * inv};
      *reinterpret_cast<float4*>(&op[8 * rr + 4 * hi + 32]) = o1;
    }
  }
}

// ---------------------------------------------------------------------------
extern "C" void kernel_launch(void* const* d_in, const int* in_sizes, int n_in,
                              void* d_out, int out_size, void* d_ws, size_t ws_size,
                              hipStream_t stream) {
  (void)in_sizes; (void)n_in; (void)out_size; (void)ws_size;
  const float* x    = (const float*)d_in[0];
  const float* Wqkv = (const float*)d_in[1];
  const float* bias = (const float*)d_in[2];
  float* out = (float*)d_out;

  char* ws = (char*)d_ws;
  __bf16* Xb = (__bf16*)(ws);                 //  8 MB  [M][K]
  __bf16* Wb = (__bf16*)(ws + 8388608);       //  6 MB  [N][K]
  __bf16* Qb = (__bf16*)(ws + 14680064);      //  8 MB  [b,h,s,d] (pre-scaled)
  __bf16* Kb = (__bf16*)(ws + 23068672);      //  8 MB  [b,h,s,d]
  __bf16* Vt = (__bf16*)(ws + 31457280);      //  8 MB  [b,h,d,s]

  cvt_all<<<dim3(2048), dim3(256), 0, stream>>>(x, Wqkv, Xb, Wb);
  qkv_gemm<<<dim3(768), dim3(256), 0, stream>>>(Xb, Wb, bias, Qb, Kb, Vt);
  attn_fwd<<<dim3(1024), dim3(256), 0, stream>>>(Qb, Kb, Vt, out);
}

// Round 11
// 104.122 us; speedup vs baseline: 1.0328x; 1.0328x over previous
//
#include <hip/hip_runtime.h>

// Problem dims
constexpr int SEQ   = 2048;
constexpr int BATCH = 2;
constexpr int EMB   = 1024;
constexpr int NH    = 16;
constexpr int HDIM  = 64;
constexpr int MROWS = SEQ * BATCH;   // 4096
constexpr int KDIM  = EMB;           // 1024
constexpr int NCOLS = 3 * EMB;       // 3072

typedef __bf16 bf16x8 __attribute__((ext_vector_type(8)));
typedef __bf16 bf16x4 __attribute__((ext_vector_type(4)));
typedef float  f32x4  __attribute__((ext_vector_type(4)));
typedef float  f32x16 __attribute__((ext_vector_type(16)));
typedef unsigned int u32;
typedef unsigned int u32x4 __attribute__((ext_vector_type(4)));

__device__ __forceinline__ u32 cvt_pk_bf16(float lo, float hi) {
  u32 r;
  asm("v_cvt_pk_bf16_f32 %0, %1, %2" : "=v"(r) : "v"(lo), "v"(hi));
  return r;
}
__device__ __forceinline__ void pl32_swap(u32& a, u32& b) {
  asm("v_permlane32_swap_b32 %0, %1" : "+v"(a), "+v"(b));
}
// async global->LDS, 16B per lane; LDS dest = wave-uniform base + lane*16
__device__ __forceinline__ void g2l16(const __bf16* g, __bf16* l) {
  __builtin_amdgcn_global_load_lds(
      (const __attribute__((address_space(1))) void*)g,
      (__attribute__((address_space(3))) void*)l, 16, 0, 0);
}

// ---------------------------------------------------------------------------
// fp32 -> bf16 cast for BOTH x and Wqkv in one launch
// ---------------------------------------------------------------------------
constexpr int N4X = (MROWS * KDIM) / 4;   // 1048576
constexpr int N4W = (NCOLS * KDIM) / 4;   // 786432
__global__ __launch_bounds__(256) void cvt_all(
    const float* __restrict__ x, const float* __restrict__ Wq,
    __bf16* __restrict__ Xb, __bf16* __restrict__ Wb) {
  int stride = gridDim.x * blockDim.x;
  for (int i = blockIdx.x * blockDim.x + threadIdx.x; i < N4X + N4W; i += stride) {
    const float4 v = (i < N4X) ? reinterpret_cast<const float4*>(x)[i]
                               : reinterpret_cast<const float4*>(Wq)[i - N4X];
    bf16x4 o;
    o[0] = (__bf16)v.x; o[1] = (__bf16)v.y; o[2] = (__bf16)v.z; o[3] = (__bf16)v.w;
    if (i < N4X) reinterpret_cast<bf16x4*>(Xb)[i] = o;
    else         reinterpret_cast<bf16x4*>(Wb)[i - N4X] = o;
  }
}

// ---------------------------------------------------------------------------
// QKV projection (R4-verified): 128x128 tile, BK=32, 2-phase double-buffered
// global_load_lds staging.
// ---------------------------------------------------------------------------
__global__ __launch_bounds__(256, 4) void qkv_gemm(
    const __bf16* __restrict__ Xb, const __bf16* __restrict__ Wb,
    const float* __restrict__ bqkv,
    __bf16* __restrict__ Qb, __bf16* __restrict__ Kb, __bf16* __restrict__ Vt) {
  __shared__ __attribute__((aligned(16))) __bf16 Al[2][128 * 32];
  __shared__ __attribute__((aligned(16))) __bf16 Bl[2][128 * 32];

  const int tid  = threadIdx.x;
  const int lane = tid & 63;
  const int w    = tid >> 6;
  const int wm   = w >> 1, wn = w & 1;

  const int bid  = blockIdx.x;
  const int wgid = (bid & 7) * 96 + (bid >> 3);
  const int nx   = wgid % 24;
  const int nyy  = wgid / 24;
  const int m0   = nyy * 128;
  const int n0   = nx * 128;

  f32x4 acc[4][4] = {};

  auto stage = [&](int buf, int kt) {
#pragma unroll
    for (int c = 0; c < 2; ++c) {
      const int u   = (w * 2 + c) * 64 + lane;
      const int row = u >> 2;
      const int sc  = ((u & 3) ^ ((row >> 1) & 3)) * 8;
      g2l16(&Xb[(size_t)(m0 + row) * KDIM + kt * 32 + sc], &Al[buf][(w * 2 + c) * 512]);
      g2l16(&Wb[(size_t)(n0 + row) * KDIM + kt * 32 + sc], &Bl[buf][(w * 2 + c) * 512]);
    }
  };

  stage(0, 0);
  __syncthreads();

  const int l15 = lane & 15, hi4 = lane >> 4;
  const int cswz = (hi4 ^ ((l15 >> 1) & 3)) * 8;

  for (int kt = 0; kt < KDIM / 32; ++kt) {
    const int buf = kt & 1;
    if (kt + 1 < KDIM / 32) stage(buf ^ 1, kt + 1);

    bf16x8 af[4], bfr[4];
#pragma unroll
    for (int i = 0; i < 4; ++i) {
      af[i]  = *reinterpret_cast<const bf16x8*>(&Al[buf][(wm * 64 + i * 16 + l15) * 32 + cswz]);
      bfr[i] = *reinterpret_cast<const bf16x8*>(&Bl[buf][(wn * 64 + i * 16 + l15) * 32 + cswz]);
    }
    __builtin_amdgcn_s_setprio(1);
#pragma unroll
    for (int i = 0; i < 4; ++i)
#pragma unroll
      for (int j = 0; j < 4; ++j)
        acc[i][j] = __builtin_amdgcn_mfma_f32_16x16x32_bf16(af[i], bfr[j], acc[i][j], 0, 0, 0);
    __builtin_amdgcn_s_setprio(0);
    __syncthreads();
  }

  const float QSCALE = 0.18033688011112042f;  // 0.125 * log2(e)
#pragma unroll
  for (int j = 0; j < 4; ++j) {
    const int f    = n0 + wn * 64 + j * 16 + l15;
    const float bias = bqkv[f];
    const int sec  = f >> 10;
    const int hd   = f & 1023;
    const int h    = hd >> 6, d = hd & 63;
#pragma unroll
    for (int i = 0; i < 4; ++i) {
#pragma unroll
      for (int r = 0; r < 4; ++r) {
        const int mm = m0 + wm * 64 + i * 16 + hi4 * 4 + r;
        const int s_ = mm >> 1, b_ = mm & 1;
        const int bh = b_ * NH + h;
        const float val = acc[i][j][r] + bias;
        if (sec == 0) {
          Qb[((size_t)bh * SEQ + s_) * HDIM + d] = (__bf16)(val * QSCALE);
        } else if (sec == 1) {
          Kb[((size_t)bh * SEQ + s_) * HDIM + d] = (__bf16)val;
        } else {
          Vt[((size_t)bh * HDIM + d) * SEQ + s_] = (__bf16)val;
        }
      }
    }
  }
}

// ---------------------------------------------------------------------------
// Flash attention v11: 64-q waves — each K/V ds_read feeds TWO MFMAs (two
// 32-q B-operand sets per wave), halving LDS-read traffic per FLOP (the
// R10-diagnosed bottleneck). Block = 4 waves = 2 q-groups (qs) x 2 t-halves
// (ts); max-free softmax (R9-verified) makes the cross-ts merge a plain add.
// 512 blocks, staging DMA at R9 level. Sync skeleton identical to R9/R10.
// ---------------------------------------------------------------------------
__global__ __launch_bounds__(256) void attn_fwd(
    const __bf16* __restrict__ Qb, const __bf16* __restrict__ Kb,
    const __bf16* __restrict__ Vt, float* __restrict__ out) {
  __shared__ __attribute__((aligned(16))) __bf16 lds[16384];  // 2 x (K 8KB + V 8KB)

  const int tid  = threadIdx.x;
  const int lane = tid & 63;
  const int w    = tid >> 6;   // 0..3
  const int qs   = w & 1;      // q-group (64 q each)
  const int ts   = w >> 1;     // t-half of each staged 64-t tile
  const int lq   = lane & 31;
  const int hi   = lane >> 5;

  // bijective XCD swizzle: 512 blocks, 64 per XCD -> 4 consecutive bh per XCD
  const int bid  = blockIdx.x;
  const int wgid = (bid & 7) * 64 + (bid >> 3);
  const int qi   = wgid & 15;
  const int bh   = wgid >> 4;
  const int b_   = bh >> 4, h = bh & 15;
  const int q0   = qi * 128 + qs * 64;

  const __bf16* Qp = Qb + (size_t)bh * SEQ * HDIM;
  const __bf16* Kp = Kb + (size_t)bh * SEQ * HDIM;
  const __bf16* Vp = Vt + (size_t)bh * HDIM * SEQ;

  // Q persistent: two 32-q B-operand sets; col q = q0 + u*32 + (lane&31)
  bf16x8 qf0[4], qf1[4];
#pragma unroll
  for (int ks = 0; ks < 4; ++ks) {
    qf0[ks] = *reinterpret_cast<const bf16x8*>(&Qp[(size_t)(q0 + lq) * HDIM + ks * 16 + hi * 8]);
    qf1[ks] = *reinterpret_cast<const bf16x8*>(&Qp[(size_t)(q0 + 32 + lq) * HDIM + ks * 16 + hi * 8]);
  }

  // acc[qsub][dblock], named statically (no runtime indexing)
  f32x16 accA0 = {}, accA1 = {}, accB0 = {}, accB1 = {};
  float l0 = 0.f, l1 = 0.f;

  auto stage = [&](int b, int t0) {
#pragma unroll
    for (int c = 0; c < 2; ++c) {
      const int u   = (w * 2 + c) * 64 + lane;            // 0..511 chunks
      const int row = u >> 3;
      const int sc  = ((u & 7) * 8) ^ ((row & 7) << 3);
      g2l16(Kp + (size_t)(t0 + row) * HDIM + sc, lds + b * 8192 + (w * 2 + c) * 512);
      g2l16(Vp + (size_t)row * SEQ + t0 + sc,    lds + b * 8192 + 4096 + (w * 2 + c) * 512);
    }
  };

  stage(0, 0);
  __syncthreads();
  int cur = 0;

  const int krow = ts * 32 + lq;  // this wave's K t-row within the staged tile

  for (int t0 = 0; t0 < SEQ; t0 += 64) {
    if (t0 + 64 < SEQ) stage(cur ^ 1, t0 + 64);  // prefetch flies under compute
    const __bf16* kb = lds + cur * 8192;
    const __bf16* vb = kb + 4096;

    // ---- S = K(t-half) · Q^T : each K read feeds both q-sets ----
    f32x16 S0 = {}, S1 = {};
    __builtin_amdgcn_s_setprio(1);
#pragma unroll
    for (int ks = 0; ks < 4; ++ks) {
      const int colb = ks * 16 + hi * 8;
      bf16x8 kf = *reinterpret_cast<const bf16x8*>(&kb[krow * 64 + (colb ^ ((krow & 7) << 3))]);
      S0 = __builtin_amdgcn_mfma_f32_32x32x16_bf16(kf, qf0[ks], S0, 0, 0, 0);
      S1 = __builtin_amdgcn_mfma_f32_32x32x16_bf16(kf, qf1[ks], S1, 0, 0, 0);
    }
    __builtin_amdgcn_s_setprio(0);

    // ---- max-free softmax: P = exp2(S); separate l per q-set ----
    float r0 = 0.f, r1 = 0.f, r2 = 0.f, r3 = 0.f;
#pragma unroll
    for (int i = 0; i < 4; ++i) {
      S0[i]      = __builtin_amdgcn_exp2f(S0[i]);      r0 += S0[i];
      S0[i + 4]  = __builtin_amdgcn_exp2f(S0[i + 4]);  r1 += S0[i + 4];
      S0[i + 8]  = __builtin_amdgcn_exp2f(S0[i + 8]);  r2 += S0[i + 8];
      S0[i + 12] = __builtin_amdgcn_exp2f(S0[i + 12]); r3 += S0[i + 12];
    }
    l0 += (r0 + r1) + (r2 + r3);
    float u0 = 0.f, u1 = 0.f, u2 = 0.f, u3 = 0.f;
#pragma unroll
    for (int i = 0; i < 4; ++i) {
      S1[i]      = __builtin_amdgcn_exp2f(S1[i]);      u0 += S1[i];
      S1[i + 4]  = __builtin_amdgcn_exp2f(S1[i + 4]);  u1 += S1[i + 4];
      S1[i + 8]  = __builtin_amdgcn_exp2f(S1[i + 8]);  u2 += S1[i + 8];
      S1[i + 12] = __builtin_amdgcn_exp2f(S1[i + 12]); u3 += S1[i + 12];
    }
    l1 += (u0 + u1) + (u2 + u3);

    // ---- P -> bf16 B-fragments (cvt_pk + permlane32_swap), per q-set ----
    bf16x8 pw0[2], pw1[2];
    {
      auto mk = [&](const f32x16& P, bf16x8* dst) {
#pragma unroll
        for (int kk = 0; kk < 2; ++kk) {
          u32 a0 = cvt_pk_bf16(P[kk * 8 + 0], P[kk * 8 + 1]);
          u32 b0 = cvt_pk_bf16(P[kk * 8 + 4], P[kk * 8 + 5]);
          u32 a1 = cvt_pk_bf16(P[kk * 8 + 2], P[kk * 8 + 3]);
          u32 b1 = cvt_pk_bf16(P[kk * 8 + 6], P[kk * 8 + 7]);
          pl32_swap(a0, b0);
          pl32_swap(a1, b1);
          u32x4 wv; wv[0] = a0; wv[1] = a1; wv[2] = b0; wv[3] = b1;
          dst[kk] = __builtin_bit_cast(bf16x8, wv);
        }
      };
      mk(S0, pw0);
      mk(S1, pw1);
    }

    // ---- O^T += V^T · P^T : each V read feeds both q-sets ----
    __builtin_amdgcn_s_setprio(1);
#pragma unroll
    for (int kk = 0; kk < 2; ++kk) {
      const int colb = ts * 32 + kk * 16 + hi * 8;
      bf16x8 v0 = *reinterpret_cast<const bf16x8*>(&vb[lq * 64        + (colb ^ ((lq & 7) << 3))]);
      bf16x8 v1 = *reinterpret_cast<const bf16x8*>(&vb[(32 + lq) * 64 + (colb ^ ((lq & 7) << 3))]);
      accA0 = __builtin_amdgcn_mfma_f32_32x32x16_bf16(v0, pw0[kk], accA0, 0, 0, 0);
      accA1 = __builtin_amdgcn_mfma_f32_32x32x16_bf16(v1, pw0[kk], accA1, 0, 0, 0);
      accB0 = __builtin_amdgcn_mfma_f32_32x32x16_bf16(v0, pw1[kk], accB0, 0, 0, 0);
      accB1 = __builtin_amdgcn_mfma_f32_32x32x16_bf16(v1, pw1[kk], accB1, 0, 0, 0);
    }
    __builtin_amdgcn_s_setprio(0);

    __syncthreads();  // readers done with cur + prefetch arrived
    cur ^= 1;
  }

  // ---- merge t-halves (plain add, max-free) in two phases through LDS ----
  float* xch = reinterpret_cast<float*>(lds);  // staging quiescent now
  const int base = qs * (64 * 33) + lane * 33; // stride 33: conflict-free

  if (ts == 1) {
#pragma unroll
    for (int i = 0; i < 16; ++i) { xch[base + i] = accA0[i]; xch[base + 16 + i] = accA1[i]; }
    xch[base + 32] = l0;
  }
  __syncthreads();
  if (ts == 0) {
#pragma unroll
    for (int i = 0; i < 16; ++i) { accA0[i] += xch[base + i]; accA1[i] += xch[base + 16 + i]; }
    l0 += xch[base + 32];
  }
  __syncthreads();
  if (ts == 1) {
#pragma unroll
    for (int i = 0; i < 16; ++i) { xch[base + i] = accB0[i]; xch[base + 16 + i] = accB1[i]; }
    xch[base + 32] = l1;
  }
  __syncthreads();
  if (ts == 0) {
#pragma unroll
    for (int i = 0; i < 16; ++i) { accB0[i] += xch[base + i]; accB1[i] += xch[base + 16 + i]; }
    l1 += xch[base + 32];

    // ---- epilogue: per q-set, combine l across lane halves and store ----
    l0 += __shfl_xor(l0, 32);
    l1 += __shfl_xor(l1, 32);
    const float inv0 = 1.0f / l0;
    const float inv1 = 1.0f / l1;

    const int sA = q0 + lq;
    float* opA = out + ((size_t)sA * BATCH + b_) * EMB + h * HDIM;
#pragma unroll
    for (int rr = 0; rr < 4; ++rr) {
      float4 o0 = {accA0[4 * rr] * inv0, accA0[4 * rr + 1] * inv0,
                   accA0[4 * rr + 2] * inv0, accA0[4 * rr + 3] * inv0};
      *reinterpret_cast<float4*>(&opA[8 * rr + 4 * hi]) = o0;
      float4 o1 = {accA1[4 * rr] * inv0, accA1[4 * rr + 1] * inv0,
                   accA1[4 * rr + 2] * inv0, accA1[4 * rr + 3] * inv0};
      *reinterpret_cast<float4*>(&opA[8 * rr + 4 * hi + 32]) = o1;
    }

    const int sB = q0 + 32 + lq;
    float* opB = out + ((size_t)sB * BATCH + b_) * EMB + h * HDIM;
#pragma unroll
    for (int rr = 0; rr < 4; ++rr) {
      float4 o0 = {accB0[4 * rr] * inv1, accB0[4 * rr + 1] * inv1,
                   accB0[4 * rr + 2] * inv1, accB0[4 * rr + 3] * inv1};
      *reinterpret_cast<float4*>(&opB[8 * rr + 4 * hi]) = o0;
      float4 o1 = {accB1[4 * rr] * inv1, accB1[4 * rr + 1] * inv1,
                   accB1[4 * rr + 2] * inv1, accB1[4 * rr + 3] * inv1};
      *reinterpret_cast<float4*>(&opB[8 * rr + 4 * hi + 32]) = o1;
    }
  }
}

// ---------------------------------------------------------------------------
extern "C" void kernel_launch(void* const* d_in, const int* in_sizes, int n_in,
                              void* d_out, int out_size, void* d_ws, size_t ws_size,
                              hipStream_t stream) {
  (void)in_sizes; (void)n_in; (void)out_size; (void)ws_size;
  const float* x    = (const float*)d_in[0];
  const float* Wqkv = (const float*)d_in[1];
  const float* bias = (const float*)d_in[2];
  float* out = (float*)d_out;

  char* ws = (char*)d_ws;
  __bf16* Xb = (__bf16*)(ws);                 //  8 MB  [M][K]
  __bf16* Wb = (__bf16*)(ws + 8388608);       //  6 MB  [N][K]
  __bf16* Qb = (__bf16*)(ws + 14680064);      //  8 MB  [b,h,s,d] (pre-scaled)
  __bf16* Kb = (__bf16*)(ws + 23068672);      //  8 MB  [b,h,s,d]
  __bf16* Vt = (__bf16*)(ws + 31457280);      //  8 MB  [b,h,d,s]

  cvt_all<<<dim3(2048), dim3(256), 0, stream>>>(x, Wqkv, Xb, Wb);
  qkv_gemm<<<dim3(768), dim3(256), 0, stream>>>(Xb, Wb, bias, Qb, Kb, Vt);
  attn_fwd<<<dim3(512), dim3(256), 0, stream>>>(Qb, Kb, Vt, out);
}